// Round 1
// baseline (489.301 us; speedup 1.0000x reference)
//
#include <hip/hip_runtime.h>

#define N_TOK 65536
#define D 64
#define C_CODES 2048
#define DECAYF 0.8f
#define OMDF 0.2f
#define EPSF 1e-5f
#define NCHUNK 4
#define CHUNK (C_CODES / NCHUNK)

// output layout (floats), concatenated in reference return order
#define OUT_QUANT 0
#define OUT_IND   (N_TOK * D)               // 4194304
#define OUT_EMB   (OUT_IND + N_TOK)         // 4259840
#define OUT_CS    (OUT_EMB + C_CODES * D)   // 4390912
#define OUT_EAVG  (OUT_CS + C_CODES)        // 4392960

__global__ void e2_kernel(const float* __restrict__ emb, float* __restrict__ e2) {
    int c = blockIdx.x * blockDim.x + threadIdx.x;
    const float4* er = (const float4*)(emb + (size_t)c * D);
    float s0 = 0.f, s1 = 0.f, s2 = 0.f, s3 = 0.f;
#pragma unroll
    for (int i = 0; i < D / 4; ++i) {
        float4 e = er[i];
        s0 = fmaf(e.x, e.x, s0);
        s1 = fmaf(e.y, e.y, s1);
        s2 = fmaf(e.z, e.z, s2);
        s3 = fmaf(e.w, e.w, s3);
    }
    e2[c] = (s0 + s1) + (s2 + s3);
}

// Each thread: one token, one chunk of 512 codes. Embedding access is
// wave-uniform (same c for all lanes) -> compiler scalarizes to s_load,
// inner loop is v_fmac_f32 (VGPR x, SGPR e).
__global__ void dist_kernel(const float* __restrict__ x, const float* __restrict__ emb,
                            const float* __restrict__ e2,
                            unsigned long long* __restrict__ keys) {
    int token = blockIdx.x * blockDim.x + threadIdx.x;
    int chunk = blockIdx.y;
    const float4* xr = (const float4*)(x + (size_t)token * D);
    float4 xv[D / 4];
#pragma unroll
    for (int i = 0; i < D / 4; ++i) xv[i] = xr[i];
    float s0 = 0.f, s1 = 0.f, s2 = 0.f, s3 = 0.f;
#pragma unroll
    for (int i = 0; i < D / 4; ++i) {
        s0 = fmaf(xv[i].x, xv[i].x, s0);
        s1 = fmaf(xv[i].y, xv[i].y, s1);
        s2 = fmaf(xv[i].z, xv[i].z, s2);
        s3 = fmaf(xv[i].w, xv[i].w, s3);
    }
    float x2 = (s0 + s1) + (s2 + s3);

    unsigned long long best = ~0ull;
    int c0 = chunk * CHUNK;
    for (int c = c0; c < c0 + CHUNK; ++c) {
        const float4* er = (const float4*)(emb + (size_t)c * D);
        float d0 = 0.f, d1 = 0.f, d2 = 0.f, d3 = 0.f;
#pragma unroll
        for (int i = 0; i < D / 4; ++i) {
            float4 e = er[i];
            d0 = fmaf(xv[i].x, e.x, d0);
            d1 = fmaf(xv[i].y, e.y, d1);
            d2 = fmaf(xv[i].z, e.z, d2);
            d3 = fmaf(xv[i].w, e.w, d3);
        }
        float dot = (d0 + d1) + (d2 + d3);
        float dist2 = x2 + e2[c] - 2.0f * dot;
        dist2 = fmaxf(dist2, 0.0f);
        // dist2 >= 0 -> IEEE bit pattern is monotone; tie -> smaller c wins,
        // matching jnp.argmax first-occurrence semantics.
        unsigned long long key =
            ((unsigned long long)__float_as_uint(dist2) << 32) | (unsigned int)c;
        best = key < best ? key : best;
    }
    keys[(size_t)chunk * N_TOK + token] = best;
}

__global__ void finalize_kernel(const unsigned long long* __restrict__ keys,
                                int* __restrict__ idx, float* __restrict__ out,
                                float* __restrict__ counts) {
    __shared__ float lcount[C_CODES];
    for (int i = threadIdx.x; i < C_CODES; i += blockDim.x) lcount[i] = 0.0f;
    __syncthreads();
    int n = blockIdx.x * blockDim.x + threadIdx.x;
    unsigned long long best = keys[n];
#pragma unroll
    for (int j = 1; j < NCHUNK; ++j) {
        unsigned long long k = keys[(size_t)j * N_TOK + n];
        best = k < best ? k : best;
    }
    int c = (int)(best & 0xffffffffull);
    idx[n] = c;
    out[OUT_IND + n] = (float)c;
    atomicAdd(&lcount[c], 1.0f);
    __syncthreads();
    for (int i = threadIdx.x; i < C_CODES; i += blockDim.x) {
        float v = lcount[i];
        if (v != 0.0f) atomicAdd(&counts[i], v);
    }
}

// 16 threads per token (one float4 each): gather quantize + scatter embed_sum.
__global__ void gather_scatter_kernel(const float* __restrict__ x,
                                      const float* __restrict__ emb,
                                      const int* __restrict__ idx,
                                      float* __restrict__ out,
                                      float* __restrict__ embed_sum) {
    int g = blockIdx.x * blockDim.x + threadIdx.x;  // [0, N_TOK*16)
    int n = g >> 4;
    int j = g & 15;
    int c = idx[n];
    float4 e = ((const float4*)emb)[c * (D / 4) + j];
    ((float4*)(out + OUT_QUANT))[g] = e;
    float4 xv = ((const float4*)x)[g];
    float* es = embed_sum + (size_t)c * D + j * 4;
    atomicAdd(es + 0, xv.x);
    atomicAdd(es + 1, xv.y);
    atomicAdd(es + 2, xv.z);
    atomicAdd(es + 3, xv.w);
}

__global__ void ema_cluster_kernel(const float* __restrict__ cluster_size,
                                   const float* __restrict__ counts,
                                   float* __restrict__ out,
                                   float* __restrict__ smoothed) {
    __shared__ float red[256];
    float ncs_loc[C_CODES / 256];
    float local = 0.0f;
#pragma unroll
    for (int t = 0; t < C_CODES / 256; ++t) {
        int i = t * 256 + threadIdx.x;
        float ncs = cluster_size[i] * DECAYF + counts[i] * OMDF;
        ncs_loc[t] = ncs;
        out[OUT_CS + i] = ncs;
        local += ncs;
    }
    red[threadIdx.x] = local;
    __syncthreads();
    for (int s = 128; s > 0; s >>= 1) {
        if ((int)threadIdx.x < s) red[threadIdx.x] += red[threadIdx.x + s];
        __syncthreads();
    }
    float tot = red[0];
#pragma unroll
    for (int t = 0; t < C_CODES / 256; ++t) {
        int i = t * 256 + threadIdx.x;
        smoothed[i] = (ncs_loc[t] + EPSF) / (tot + (float)C_CODES * EPSF) * tot;
    }
}

__global__ void ema_embed_kernel(const float* __restrict__ embed_avg,
                                 const float* __restrict__ embed_sum,
                                 const float* __restrict__ smoothed,
                                 float* __restrict__ out) {
    int g = blockIdx.x * blockDim.x + threadIdx.x;  // [0, C_CODES*16)
    int c = g >> 4;
    float4 ea = ((const float4*)embed_avg)[g];
    float4 es = ((const float4*)embed_sum)[g];
    float4 na;
    na.x = ea.x * DECAYF + es.x * OMDF;
    na.y = ea.y * DECAYF + es.y * OMDF;
    na.z = ea.z * DECAYF + es.z * OMDF;
    na.w = ea.w * DECAYF + es.w * OMDF;
    ((float4*)(out + OUT_EAVG))[g] = na;
    float sm = smoothed[c];
    float4 ne;
    ne.x = na.x / sm;
    ne.y = na.y / sm;
    ne.z = na.z / sm;
    ne.w = na.w / sm;
    ((float4*)(out + OUT_EMB))[g] = ne;
}

extern "C" void kernel_launch(void* const* d_in, const int* in_sizes, int n_in,
                              void* d_out, int out_size, void* d_ws, size_t ws_size,
                              hipStream_t stream) {
    const float* x            = (const float*)d_in[0];  // (16,4096,64)
    const float* emb          = (const float*)d_in[1];  // (1,2048,64)
    const float* cluster_size = (const float*)d_in[2];  // (1,2048)
    const float* embed_avg    = (const float*)d_in[3];  // (1,2048,64)
    float* out = (float*)d_out;

    // workspace layout
    float* e2        = (float*)d_ws;             // 2048
    float* counts    = e2 + C_CODES;             // 2048  (zeroed)
    float* embed_sum = counts + C_CODES;         // 131072 (zeroed)
    float* smoothed  = embed_sum + C_CODES * D;  // 2048
    int* idx         = (int*)(smoothed + C_CODES);          // 65536 ints
    unsigned long long* keys = (unsigned long long*)(idx + N_TOK);  // 4*65536, 8B-aligned

    hipMemsetAsync(counts, 0, (size_t)(C_CODES + C_CODES * D) * sizeof(float), stream);

    e2_kernel<<<C_CODES / 256, 256, 0, stream>>>(emb, e2);
    dist_kernel<<<dim3(N_TOK / 256, NCHUNK), 256, 0, stream>>>(x, emb, e2, keys);
    finalize_kernel<<<N_TOK / 256, 256, 0, stream>>>(keys, idx, out, counts);
    gather_scatter_kernel<<<(N_TOK * 16) / 256, 256, 0, stream>>>(x, emb, idx, out, embed_sum);
    ema_cluster_kernel<<<1, 256, 0, stream>>>(cluster_size, counts, out, smoothed);
    ema_embed_kernel<<<(C_CODES * 16) / 256, 256, 0, stream>>>(embed_avg, embed_sum, smoothed, out);
}